// Round 10
// baseline (1118.790 us; speedup 1.0000x reference)
//
#include <hip/hip_runtime.h>
#include <hip/hip_bf16.h>

#define Bg 32
#define Nn 512
#define Fdim 6
#define Wd 128
#define KG 100
#define KP 3
#define DIM2 1536
#define GC16 16

typedef __hip_bfloat16 bf16;
typedef unsigned long long ull;

__device__ __forceinline__ float b2f(bf16 v) { return __bfloat162float(v); }
__device__ __forceinline__ float lrelu(float v) { return v > 0.0f ? v : 0.01f * v; }

// ---------- dtype detection (f32=1 / bf16=0), from low-half u16 bit patterns ----------
__global__ void detect_kernel(const unsigned short* __restrict__ x, int* __restrict__ flag) {
  if (threadIdx.x == 0 && blockIdx.x == 0) {
    int big = 0;
    for (int i = 0; i < 512; i += 2) {
      unsigned short u = x[i];
      int e = (u >> 7) & 0xFF;
      if (e >= 140) big++;
    }
    *flag = (big > 20) ? 1 : 0;
  }
}

// ---------- convert x -> f32 ----------
__global__ void convert_kernel(const void* __restrict__ x, float* __restrict__ xf, int n,
                               const int* __restrict__ flag) {
  int i = blockIdx.x * 256 + threadIdx.x;
  if (i >= n) return;
  if (*flag) xf[i] = ((const float*)x)[i];
  else       xf[i] = b2f(((const bf16*)x)[i]);
}

// ---------- branchless sorted-3 insert (k0<=k1<=k2 kept smallest) ----------
__device__ __forceinline__ void ins3b(ull key, ull& k0, ull& k1, ull& k2) {
  ull M0 = k0 < key ? key : k0;  k0 = k0 < key ? k0 : key;
  ull M1 = k1 < M0 ? M0 : k1;    k1 = k1 < M0 ? k1 : M0;
  k2 = k2 < M1 ? k2 : M1;
}

// ---------- kNN k=100: one wave/row; ballot-popcount radix search ----------
__global__ void knn100_kernel(const float* __restrict__ xf, int* __restrict__ nbr) {
  __shared__ float xg[Nn * 7];
  __shared__ float sqv[Nn];
  int t = threadIdx.x; int w = t >> 6; int l = t & 63;
  int row0 = blockIdx.x * 4; int g = row0 >> 9;
  const float* xp = xf + g * (Nn * Fdim);
  for (int j = t; j < Nn; j += 256) {
    float s = 0.0f;
    #pragma unroll
    for (int c = 0; c < Fdim; c++) { float v = xp[j * Fdim + c]; xg[j * 7 + c] = v; s += v * v; }
    sqv[j] = s;
  }
  __syncthreads();
  int i = (row0 & 511) + w;
  float xi[Fdim];
  #pragma unroll
  for (int c = 0; c < Fdim; c++) xi[c] = xg[i * 7 + c];
  float sqi = sqv[i];
  unsigned m[8];
  #pragma unroll
  for (int ch = 0; ch < 8; ch++) {
    int j = ch * 64 + l;
    float dot = 0.0f;
    #pragma unroll
    for (int c = 0; c < Fdim; c++) dot += xi[c] * xg[j * 7 + c];
    float d = sqi + sqv[j] - 2.0f * dot;
    if (j == i) d += 1e10f;
    unsigned u = __float_as_uint(d);
    m[ch] = (u & 0x80000000u) ? ~u : (u | 0x80000000u);
  }
  unsigned T = 0u;
  for (int b = 31; b >= 0; b--) {
    unsigned mid = T | (1u << b);
    int c = 0;
    #pragma unroll
    for (int ch = 0; ch < 8; ch++) c += __popcll(__ballot(m[ch] < mid));
    if (c < KG) T = mid;
  }
  int* outp = nbr + ((size_t)(g * Nn + i)) * KG;
  ull lmask = (1ull << l) - 1ull;
  int base = 0;
  #pragma unroll
  for (int ch = 0; ch < 8; ch++) {
    bool less = m[ch] < T;
    ull bal = __ballot(less);
    if (less) outp[base + __popcll(bal & lmask)] = ch * 64 + l;
    base += __popcll(bal);
  }
  int need = KG - base;
  int eqb = 0;
  #pragma unroll
  for (int ch = 0; ch < 8; ch++) {
    bool eq = (m[ch] == T);
    ull bal = __ballot(eq);
    int gr = eqb + __popcll(bal & lmask);
    if (eq && gr < need) outp[base + gr] = ch * 64 + l;
    eqb += __popcll(bal);
  }
}

// ---------- kNN k=3 on coords: 16 lanes/row ----------
__global__ void knn3_x_kernel(const float* __restrict__ xf, int* __restrict__ nbr) {
  __shared__ float xg[Nn * 7];
  __shared__ float sqv[Nn];
  int t = threadIdx.x; int bid = blockIdx.x;
  int g = bid >> 5;
  const float* xp = xf + g * (Nn * Fdim);
  for (int j = t; j < Nn; j += 256) {
    float s = 0.0f;
    #pragma unroll
    for (int c = 0; c < Fdim; c++) { float v = xp[j * Fdim + c]; xg[j * 7 + c] = v; s += v * v; }
    sqv[j] = s;
  }
  __syncthreads();
  int lr = t >> 4; int sub = t & 15; int l = t & 63;
  int i = ((bid & 31) << 4) + lr;
  float xi[Fdim];
  #pragma unroll
  for (int c = 0; c < Fdim; c++) xi[c] = xg[i * 7 + c];
  float sqi = sqv[i];
  ull k0 = ~0ull, k1 = ~0ull, k2 = ~0ull;
  for (int jj = 0; jj < 32; jj++) {
    int s = (jj + l) & 31;
    int j = sub * 32 + s;
    float dot = 0.0f;
    #pragma unroll
    for (int c = 0; c < Fdim; c++) dot += xi[c] * xg[j * 7 + c];
    float d = sqi + sqv[j] - 2.0f * dot;
    if (j == i) d += 1e10f;
    unsigned u = __float_as_uint(d);
    unsigned m = (u & 0x80000000u) ? ~u : (u | 0x80000000u);
    ins3b(((ull)m << 32) | (unsigned)j, k0, k1, k2);
  }
  #pragma unroll
  for (int off = 1; off <= 8; off <<= 1) {
    ull b0 = __shfl_xor(k0, off, 64);
    ull b1 = __shfl_xor(k1, off, 64);
    ull b2 = __shfl_xor(k2, off, 64);
    ins3b(b0, k0, k1, k2); ins3b(b1, k0, k1, k2); ins3b(b2, k0, k1, k2);
  }
  if (sub == 0) {
    int row = g * Nn + i;
    nbr[row * 3 + 0] = (int)(k0 & 0xFFFFFFFFu);
    nbr[row * 3 + 1] = (int)(k1 & 0xFFFFFFFFu);
    nbr[row * 3 + 2] = (int)(k2 & 0xFFFFFFFFu);
  }
}

// ---------- kNN k=3 from chunked Gram ----------
__global__ void knn3_gram_kernel(const float* __restrict__ G, int* __restrict__ nbr, int g0) {
  __shared__ float sqv[Nn];
  int t = threadIdx.x; int bid = blockIdx.x;
  int gl = bid >> 5; int g = g0 + gl;
  const float* Gg = G + (size_t)gl * Nn * Nn;
  for (int j = t; j < Nn; j += 256) sqv[j] = Gg[(size_t)j * Nn + j];
  __syncthreads();
  int lr = t >> 4; int sub = t & 15; int l = t & 63;
  int i = ((bid & 31) << 4) + lr;
  float sqi = sqv[i];
  const float* Gr = Gg + (size_t)i * Nn;
  ull k0 = ~0ull, k1 = ~0ull, k2 = ~0ull;
  for (int jj = 0; jj < 32; jj++) {
    int s = (jj + l) & 31;
    int j = sub * 32 + s;
    float d = sqi + sqv[j] - 2.0f * Gr[j];
    if (j == i) d += 1e10f;
    unsigned u = __float_as_uint(d);
    unsigned m = (u & 0x80000000u) ? ~u : (u | 0x80000000u);
    ins3b(((ull)m << 32) | (unsigned)j, k0, k1, k2);
  }
  #pragma unroll
  for (int off = 1; off <= 8; off <<= 1) {
    ull b0 = __shfl_xor(k0, off, 64);
    ull b1 = __shfl_xor(k1, off, 64);
    ull b2 = __shfl_xor(k2, off, 64);
    ins3b(b0, k0, k1, k2); ins3b(b1, k0, k1, k2); ins3b(b2, k0, k1, k2);
  }
  if (sub == 0) {
    int row = g * Nn + i;
    nbr[row * 3 + 0] = (int)(k0 & 0xFFFFFFFFu);
    nbr[row * 3 + 1] = (int)(k1 & 0xFFFFFFFFu);
    nbr[row * 3 + 2] = (int)(k2 & 0xFFFFFFFFu);
  }
}

// ---------- neighbor-mean over 100, C=6 ----------
__global__ void gm6_kernel(const float* __restrict__ src, const int* __restrict__ nbr,
                           float* __restrict__ dst) {
  __shared__ float s[Nn * Fdim];
  int g = blockIdx.x; int t = threadIdx.x;  // 512
  const float* sp = src + g * (Nn * Fdim);
  for (int idx = t; idx < Nn * Fdim; idx += 512) s[idx] = sp[idx];
  __syncthreads();
  float acc[Fdim] = {0, 0, 0, 0, 0, 0};
  const int* nb = nbr + ((size_t)(g * Nn + t)) * KG;
  for (int k = 0; k < KG; k++) {
    int j = nb[k];
    #pragma unroll
    for (int c = 0; c < Fdim; c++) acc[c] += s[j * Fdim + c];
  }
  float* dp = dst + (size_t)(g * Nn + t) * Fdim;
  #pragma unroll
  for (int c = 0; c < Fdim; c++) dp[c] = acc[c] / 100.0f;
}

// ---------- neighbor-mean over 100, C=128 ----------
__global__ void gm128_kernel(const float* __restrict__ src, const int* __restrict__ nbr,
                             float* __restrict__ dst) {
  __shared__ int ids[KG];
  int row = blockIdx.x; int g = row >> 9; int t = threadIdx.x;  // 128
  if (t < KG) ids[t] = nbr[(size_t)row * KG + t];
  __syncthreads();
  const float* sp = src + (size_t)g * Nn * Wd;
  float acc = 0.0f;
  #pragma unroll 4
  for (int k = 0; k < KG; k++) acc += sp[ids[k] * Wd + t];
  dst[(size_t)row * Wd + t] = acc / 100.0f;
}

// ---------- out = lrelu(in0@W[0]+in1@W[1]+in2@W[2]+b); LDS staging + f4 reads ----------
__global__ void proj3_kernel(const float* __restrict__ in0, const float* __restrict__ in1,
                             const float* __restrict__ in2, const void* __restrict__ Wt_,
                             const void* __restrict__ bt_, float* __restrict__ out, int C,
                             long Woff, long boff, const int* __restrict__ flag) {
  __shared__ __align__(16) float s0[8 * 128], s1[8 * 128], s2[8 * 128];
  int t = threadIdx.x;  // 128
  int node0 = blockIdx.x * 8;
  int f32 = *flag;
  float acc[8] = {0, 0, 0, 0, 0, 0, 0, 0};
  float bd;
  if (C == 128) {
    const float4* q0 = (const float4*)(in0 + (size_t)node0 * 128);
    const float4* q1 = (const float4*)(in1 + (size_t)node0 * 128);
    const float4* q2 = (const float4*)(in2 + (size_t)node0 * 128);
    #pragma unroll
    for (int it = 0; it < 2; it++) {
      ((float4*)s0)[t + it * 128] = q0[t + it * 128];
      ((float4*)s1)[t + it * 128] = q1[t + it * 128];
      ((float4*)s2)[t + it * 128] = q2[t + it * 128];
    }
    __syncthreads();
    if (f32) {
      const float* W = (const float*)Wt_ + Woff;
      for (int c0 = 0; c0 < 128; c0 += 4) {
        float w0[4], w1[4], w2[4];
        #pragma unroll
        for (int q = 0; q < 4; q++) {
          w0[q] = W[(c0 + q) * 128 + t];
          w1[q] = W[(128 + c0 + q) * 128 + t];
          w2[q] = W[(256 + c0 + q) * 128 + t];
        }
        #pragma unroll
        for (int n = 0; n < 8; n++) {
          float4 a0 = *(const float4*)&s0[n * 128 + c0];
          float4 a1 = *(const float4*)&s1[n * 128 + c0];
          float4 a2 = *(const float4*)&s2[n * 128 + c0];
          acc[n] += a0.x * w0[0] + a0.y * w0[1] + a0.z * w0[2] + a0.w * w0[3]
                  + a1.x * w1[0] + a1.y * w1[1] + a1.z * w1[2] + a1.w * w1[3]
                  + a2.x * w2[0] + a2.y * w2[1] + a2.z * w2[2] + a2.w * w2[3];
        }
      }
      bd = ((const float*)bt_ + boff)[t];
    } else {
      const bf16* W = (const bf16*)Wt_ + Woff;
      for (int c0 = 0; c0 < 128; c0 += 4) {
        float w0[4], w1[4], w2[4];
        #pragma unroll
        for (int q = 0; q < 4; q++) {
          w0[q] = b2f(W[(c0 + q) * 128 + t]);
          w1[q] = b2f(W[(128 + c0 + q) * 128 + t]);
          w2[q] = b2f(W[(256 + c0 + q) * 128 + t]);
        }
        #pragma unroll
        for (int n = 0; n < 8; n++) {
          float4 a0 = *(const float4*)&s0[n * 128 + c0];
          float4 a1 = *(const float4*)&s1[n * 128 + c0];
          float4 a2 = *(const float4*)&s2[n * 128 + c0];
          acc[n] += a0.x * w0[0] + a0.y * w0[1] + a0.z * w0[2] + a0.w * w0[3]
                  + a1.x * w1[0] + a1.y * w1[1] + a1.z * w1[2] + a1.w * w1[3]
                  + a2.x * w2[0] + a2.y * w2[1] + a2.z * w2[2] + a2.w * w2[3];
        }
      }
      bd = b2f(((const bf16*)bt_ + boff)[t]);
    }
  } else {  // C == 6
    if (t < 48) {
      s0[t] = in0[(size_t)node0 * 6 + t];
      s1[t] = in1[(size_t)node0 * 6 + t];
      s2[t] = in2[(size_t)node0 * 6 + t];
    }
    __syncthreads();
    if (f32) {
      const float* W = (const float*)Wt_ + Woff;
      for (int c = 0; c < 6; c++) {
        float w0 = W[c * 128 + t], w1 = W[(6 + c) * 128 + t], w2 = W[(12 + c) * 128 + t];
        #pragma unroll
        for (int n = 0; n < 8; n++)
          acc[n] += s0[n * 6 + c] * w0 + s1[n * 6 + c] * w1 + s2[n * 6 + c] * w2;
      }
      bd = ((const float*)bt_ + boff)[t];
    } else {
      const bf16* W = (const bf16*)Wt_ + Woff;
      for (int c = 0; c < 6; c++) {
        float w0 = b2f(W[c * 128 + t]), w1 = b2f(W[(6 + c) * 128 + t]), w2 = b2f(W[(12 + c) * 128 + t]);
        #pragma unroll
        for (int n = 0; n < 8; n++)
          acc[n] += s0[n * 6 + c] * w0 + s1[n * 6 + c] * w1 + s2[n * 6 + c] * w2;
      }
      bd = b2f(((const bf16*)bt_ + boff)[t]);
    }
  }
  #pragma unroll
  for (int n = 0; n < 8; n++)
    out[(size_t)(node0 + n) * 128 + t] = lrelu(acc[n] + bd);
}

// ---------- u = in@W[0:C], v = in@W[C:2C]; LDS staging + f4 reads ----------
__global__ void proj_dual_kernel(const float* __restrict__ in, const void* __restrict__ Wt_,
                                 float* __restrict__ u, float* __restrict__ v, int C,
                                 long Woff, const int* __restrict__ flag) {
  __shared__ __align__(16) float s0[8 * 128];
  int t = threadIdx.x; int node0 = blockIdx.x * 8;
  int f32 = *flag;
  float au[8] = {0, 0, 0, 0, 0, 0, 0, 0};
  float av[8] = {0, 0, 0, 0, 0, 0, 0, 0};
  if (C == 128) {
    const float4* qp = (const float4*)(in + (size_t)node0 * 128);
    #pragma unroll
    for (int it = 0; it < 2; it++) ((float4*)s0)[t + it * 128] = qp[t + it * 128];
    __syncthreads();
    if (f32) {
      const float* W = (const float*)Wt_ + Woff;
      for (int c0 = 0; c0 < 128; c0 += 4) {
        float wa[4], wb[4];
        #pragma unroll
        for (int q = 0; q < 4; q++) {
          wa[q] = W[(c0 + q) * 128 + t];
          wb[q] = W[(128 + c0 + q) * 128 + t];
        }
        #pragma unroll
        for (int n = 0; n < 8; n++) {
          float4 a0 = *(const float4*)&s0[n * 128 + c0];
          au[n] += a0.x * wa[0] + a0.y * wa[1] + a0.z * wa[2] + a0.w * wa[3];
          av[n] += a0.x * wb[0] + a0.y * wb[1] + a0.z * wb[2] + a0.w * wb[3];
        }
      }
    } else {
      const bf16* W = (const bf16*)Wt_ + Woff;
      for (int c0 = 0; c0 < 128; c0 += 4) {
        float wa[4], wb[4];
        #pragma unroll
        for (int q = 0; q < 4; q++) {
          wa[q] = b2f(W[(c0 + q) * 128 + t]);
          wb[q] = b2f(W[(128 + c0 + q) * 128 + t]);
        }
        #pragma unroll
        for (int n = 0; n < 8; n++) {
          float4 a0 = *(const float4*)&s0[n * 128 + c0];
          au[n] += a0.x * wa[0] + a0.y * wa[1] + a0.z * wa[2] + a0.w * wa[3];
          av[n] += a0.x * wb[0] + a0.y * wb[1] + a0.z * wb[2] + a0.w * wb[3];
        }
      }
    }
  } else {  // C == 6
    if (t < 48) s0[t] = in[(size_t)node0 * 6 + t];
    __syncthreads();
    if (f32) {
      const float* W = (const float*)Wt_ + Woff;
      for (int c = 0; c < 6; c++) {
        float wa = W[c * 128 + t], wb = W[(6 + c) * 128 + t];
        #pragma unroll
        for (int n = 0; n < 8; n++) { float x = s0[n * 6 + c]; au[n] += x * wa; av[n] += x * wb; }
      }
    } else {
      const bf16* W = (const bf16*)Wt_ + Woff;
      for (int c = 0; c < 6; c++) {
        float wa = b2f(W[c * 128 + t]), wb = b2f(W[(6 + c) * 128 + t]);
        #pragma unroll
        for (int n = 0; n < 8; n++) { float x = s0[n * 6 + c]; au[n] += x * wa; av[n] += x * wb; }
      }
    }
  }
  #pragma unroll
  for (int n = 0; n < 8; n++) {
    u[(size_t)(node0 + n) * 128 + t] = au[n];
    v[(size_t)(node0 + n) * 128 + t] = av[n];
  }
}

// ---------- edgeconv1: float4 tl reads + batched weight loads ----------
__global__ void edge_mlp1_kernel(const float* __restrict__ u, const float* __restrict__ v,
                                 const int* __restrict__ nbrp, const void* __restrict__ W2_,
                                 const void* __restrict__ b1_, const void* __restrict__ b2_,
                                 float* __restrict__ y, const int* __restrict__ flag) {
  __shared__ __align__(16) float tl[8][3][128];
  int t = threadIdx.x; int node0 = blockIdx.x * 8; int g = node0 >> 9;
  int f32 = *flag;
  float b1d;
  if (f32) b1d = ((const float*)b1_)[t]; else b1d = b2f(((const bf16*)b1_)[t]);
  for (int n = 0; n < 8; n++) {
    int row = node0 + n;
    float ui = u[(size_t)row * 128 + t], vi = v[(size_t)row * 128 + t];
    #pragma unroll
    for (int k = 0; k < 3; k++) {
      int j = nbrp[row * 3 + k];
      tl[n][k][t] = lrelu(ui + v[(size_t)(g * Nn + j) * 128 + t] - vi + b1d);
    }
  }
  __syncthreads();
  float acc[8][3];
  #pragma unroll
  for (int n = 0; n < 8; n++)
    #pragma unroll
    for (int k = 0; k < 3; k++) acc[n][k] = 0.0f;
  if (f32) {
    const float* W = (const float*)W2_;
    for (int c0 = 0; c0 < 128; c0 += 4) {
      float wv[4];
      #pragma unroll
      for (int q = 0; q < 4; q++) wv[q] = W[(c0 + q) * 128 + t];
      #pragma unroll
      for (int n = 0; n < 8; n++)
        #pragma unroll
        for (int k = 0; k < 3; k++) {
          float4 tv = *(const float4*)&tl[n][k][c0];
          acc[n][k] += tv.x * wv[0] + tv.y * wv[1] + tv.z * wv[2] + tv.w * wv[3];
        }
    }
  } else {
    const bf16* W = (const bf16*)W2_;
    for (int c0 = 0; c0 < 128; c0 += 4) {
      float wv[4];
      #pragma unroll
      for (int q = 0; q < 4; q++) wv[q] = b2f(W[(c0 + q) * 128 + t]);
      #pragma unroll
      for (int n = 0; n < 8; n++)
        #pragma unroll
        for (int k = 0; k < 3; k++) {
          float4 tv = *(const float4*)&tl[n][k][c0];
          acc[n][k] += tv.x * wv[0] + tv.y * wv[1] + tv.z * wv[2] + tv.w * wv[3];
        }
    }
  }
  float b2d;
  if (f32) b2d = ((const float*)b2_)[t]; else b2d = b2f(((const bf16*)b2_)[t]);
  #pragma unroll
  for (int n = 0; n < 8; n++) {
    float m = lrelu(acc[n][0] + b2d);
    m = fmaxf(m, lrelu(acc[n][1] + b2d));
    m = fmaxf(m, lrelu(acc[n][2] + b2d));
    y[(size_t)(node0 + n) * 128 + t] = m;
  }
}

// ---------- edgeconv2/3 ----------
__global__ void edge_max_kernel(const float* __restrict__ u, const float* __restrict__ v,
                                const int* __restrict__ nbrp, const void* __restrict__ bias_,
                                float* __restrict__ y, long boff, const int* __restrict__ flag) {
  int row = blockIdx.x; int g = row >> 9; int t = threadIdx.x;  // 128
  float ui = u[(size_t)row * 128 + t], vi = v[(size_t)row * 128 + t];
  float bd;
  if (*flag) bd = ((const float*)bias_ + boff)[t]; else bd = b2f(((const bf16*)bias_ + boff)[t]);
  float m = -3.4e38f;
  #pragma unroll
  for (int k = 0; k < 3; k++) {
    int j = nbrp[row * 3 + k];
    m = fmaxf(m, lrelu(ui - vi + v[(size_t)(g * Nn + j) * 128 + t] + bd));
  }
  y[(size_t)row * 128 + t] = m;
}

// ---------- chunked Gram matrix ----------
__global__ void gram_kernel(const float* __restrict__ y, float* __restrict__ G, int g0) {
  __shared__ float As[64][17], Bs[64][17];
  int bid = blockIdx.x;
  int gl = bid >> 6; int tt = bid & 63; int ti = tt >> 3; int tj = tt & 7;
  int g = g0 + gl;
  int t = threadIdx.x; int tx = t & 15, ty = t >> 4;
  const float* Yg = y + (size_t)g * Nn * Wd;
  float* Gg = G + (size_t)gl * Nn * Nn;
  float c[4][4];
  #pragma unroll
  for (int p = 0; p < 4; p++)
    #pragma unroll
    for (int q = 0; q < 4; q++) c[p][q] = 0.0f;
  for (int k0 = 0; k0 < 128; k0 += 16) {
    for (int idx = t; idx < 1024; idx += 256) {
      int r = idx >> 4, cc = idx & 15;
      As[r][cc] = Yg[(ti * 64 + r) * 128 + k0 + cc];
      Bs[r][cc] = Yg[(tj * 64 + r) * 128 + k0 + cc];
    }
    __syncthreads();
    for (int kk = 0; kk < 16; kk++) {
      float a[4], bb[4];
      #pragma unroll
      for (int p = 0; p < 4; p++) a[p] = As[ty * 4 + p][kk];
      #pragma unroll
      for (int q = 0; q < 4; q++) bb[q] = Bs[tx * 4 + q][kk];
      #pragma unroll
      for (int p = 0; p < 4; p++)
        #pragma unroll
        for (int q = 0; q < 4; q++) c[p][q] += a[p] * bb[q];
    }
    __syncthreads();
  }
  #pragma unroll
  for (int p = 0; p < 4; p++)
    #pragma unroll
    for (int q = 0; q < 4; q++)
      Gg[(size_t)(ti * 64 + ty * 4 + p) * Nn + tj * 64 + tx * 4 + q] = c[p][q];
}

// ---------- two-pass mean+max pool ----------
__global__ void pool1_kernel(const float* __restrict__ h, float* __restrict__ pp) {
  int b = blockIdx.x;                 // 256: g*8 + chunk
  int g = b >> 3, ch = b & 7;
  int t = threadIdx.x;                // 128
  const float* hg = h + (size_t)g * Nn * Wd + (size_t)ch * 64 * Wd;
  float s = 0.0f, m = -3.4e38f;
  #pragma unroll 4
  for (int n = 0; n < 64; n++) {
    float vv = hg[n * 128 + t];
    s += vv; m = fmaxf(m, vv);
  }
  pp[b * 256 + t] = s;
  pp[b * 256 + 128 + t] = m;
}

__global__ void pool2_kernel(const float* __restrict__ pp, float* __restrict__ z,
                             int meanoff, int maxoff) {
  int g = blockIdx.x; int t = threadIdx.x;  // 128
  float s = 0.0f, m = -3.4e38f;
  #pragma unroll
  for (int q = 0; q < 8; q++) {
    s += pp[(g * 8 + q) * 256 + t];
    m = fmaxf(m, pp[(g * 8 + q) * 256 + 128 + t]);
  }
  z[g * DIM2 + meanoff + t] = s / 512.0f;
  z[g * DIM2 + maxoff + t] = m;
}

// ---------- BatchNorm1d (batch stats), in place ----------
__global__ void bn_kernel(float* __restrict__ z, const void* __restrict__ gamma,
                          const void* __restrict__ beta, const int* __restrict__ flag) {
  int c = blockIdx.x * 256 + threadIdx.x;
  if (c >= DIM2) return;
  float s = 0.0f;
  for (int r = 0; r < Bg; r++) s += z[r * DIM2 + c];
  float mu = s / 32.0f;
  float v = 0.0f;
  for (int r = 0; r < Bg; r++) { float d = z[r * DIM2 + c] - mu; v += d * d; }
  float var = v / 32.0f;
  float gm, bt;
  if (*flag) { gm = ((const float*)gamma)[c]; bt = ((const float*)beta)[c]; }
  else       { gm = b2f(((const bf16*)gamma)[c]); bt = b2f(((const bf16*)beta)[c]); }
  float scale = gm / sqrtf(var + 1e-5f);
  for (int r = 0; r < Bg; r++) z[r * DIM2 + c] = (z[r * DIM2 + c] - mu) * scale + bt;
}

// ---------- W transpose: WT[d][k] = W[k][d], 32x32 LDS tiles ----------
__global__ void wtrans_kernel(const void* __restrict__ W_, void* __restrict__ WT_,
                              long Woff, const int* __restrict__ flag) {
  __shared__ float tf[32][33];
  __shared__ unsigned short th[32][33];
  int bx = blockIdx.x % 48, by = blockIdx.x / 48;
  int tx = threadIdx.x & 31, ty = threadIdx.x >> 5; // 32 x 8
  if (*flag) {
    const float* W = (const float*)W_ + Woff;
    float* WT = (float*)WT_;
    #pragma unroll
    for (int r = 0; r < 32; r += 8)
      tf[ty + r][tx] = W[(size_t)(by * 32 + ty + r) * DIM2 + bx * 32 + tx];
    __syncthreads();
    #pragma unroll
    for (int r = 0; r < 32; r += 8)
      WT[(size_t)(bx * 32 + ty + r) * DIM2 + by * 32 + tx] = tf[tx][ty + r];
  } else {
    const unsigned short* W = (const unsigned short*)W_ + Woff;
    unsigned short* WT = (unsigned short*)WT_;
    #pragma unroll
    for (int r = 0; r < 32; r += 8)
      th[ty + r][tx] = W[(size_t)(by * 32 + ty + r) * DIM2 + bx * 32 + tx];
    __syncthreads();
    #pragma unroll
    for (int r = 0; r < 32; r += 8)
      WT[(size_t)(bx * 32 + ty + r) * DIM2 + by * 32 + tx] = th[tx][ty + r];
  }
}

// ---------- head linear: float4 LDS reads + batched WT loads ----------
__global__ void hl_kernel(const float* __restrict__ in, const void* __restrict__ WTt,
                          const void* __restrict__ bt_, float* __restrict__ out,
                          long boff, const int* __restrict__ flag) {
  __shared__ __align__(16) float a[32 * 132];
  int t = threadIdx.x; int dcol = blockIdx.x * 8 + (t >> 5); int r = t & 31;
  int f32 = *flag;
  float acc = 0.0f;
  for (int k0 = 0; k0 < DIM2; k0 += 128) {
    for (int idx = t; idx < 4096; idx += 256) {
      int rr = idx >> 7, kk = idx & 127;
      a[rr * 132 + kk] = in[rr * DIM2 + k0 + kk];
    }
    __syncthreads();
    if (f32) {
      const float* WT = (const float*)WTt;
      for (int kk = 0; kk < 128; kk += 4) {
        float wv[4];
        #pragma unroll
        for (int q = 0; q < 4; q++) wv[q] = WT[(size_t)dcol * DIM2 + k0 + kk + q];
        float4 av = *(const float4*)&a[r * 132 + kk];
        acc += av.x * wv[0] + av.y * wv[1] + av.z * wv[2] + av.w * wv[3];
      }
    } else {
      const bf16* WT = (const bf16*)WTt;
      for (int kk = 0; kk < 128; kk += 4) {
        float wv[4];
        #pragma unroll
        for (int q = 0; q < 4; q++) wv[q] = b2f(WT[(size_t)dcol * DIM2 + k0 + kk + q]);
        float4 av = *(const float4*)&a[r * 132 + kk];
        acc += av.x * wv[0] + av.y * wv[1] + av.z * wv[2] + av.w * wv[3];
      }
    }
    __syncthreads();
  }
  float bd;
  if (f32) bd = ((const float*)bt_ + boff)[dcol]; else bd = b2f(((const bf16*)bt_ + boff)[dcol]);
  out[r * DIM2 + dcol] = lrelu(acc + bd);
}

// ---------- final ----------
__global__ void final_kernel(const float* __restrict__ zin, const void* __restrict__ outW,
                             const void* __restrict__ outb, void* __restrict__ out,
                             const int* __restrict__ flag) {
  __shared__ float red[256];
  int r = blockIdx.x, t = threadIdx.x;
  int f32 = *flag;
  float acc = 0.0f;
  if (f32) {
    const float* W = (const float*)outW;
    for (int c = t; c < DIM2; c += 256) acc += zin[r * DIM2 + c] * W[c];
  } else {
    const bf16* W = (const bf16*)outW;
    for (int c = t; c < DIM2; c += 256) acc += zin[r * DIM2 + c] * b2f(W[c]);
  }
  red[t] = acc; __syncthreads();
  for (int s = 128; s > 0; s >>= 1) { if (t < s) red[t] += red[t + s]; __syncthreads(); }
  if (t == 0) {
    float ob;
    if (f32) ob = ((const float*)outb)[0]; else ob = b2f(((const bf16*)outb)[0]);
    float val = red[0] + ob;
    if (f32) ((float*)out)[r] = val;
    else     ((bf16*)out)[r] = __float2bfloat16(val);
  }
}

extern "C" void kernel_launch(void* const* d_in, const int* in_sizes, int n_in,
                              void* d_out, int out_size, void* d_ws, size_t ws_size,
                              hipStream_t stream) {
  const void* x      = d_in[0];
  const void* tag1_W = d_in[2];
  const void* tag1_b = d_in[3];
  const void* tag_W  = d_in[4];
  const void* tag_b  = d_in[5];
  const void* p1_W1  = d_in[6];
  const void* p1_b1  = d_in[7];
  const void* p1_W2  = d_in[8];
  const void* p1_b2  = d_in[9];
  const void* pf_W   = d_in[10];
  const void* pf_b   = d_in[11];
  const void* bn_g   = d_in[12];
  const void* bn_b   = d_in[13];
  const void* lin_W  = d_in[14];
  const void* lin_b  = d_in[15];
  const void* out_W  = d_in[16];
  const void* out_b  = d_in[17];

  // ---- workspace layout: total 10,485,776 floats ≈ 40 MB ----
  float* ws = (float*)d_ws;
  float* XF   = ws + 0;                 // 98304
  float* M16  = ws + 98304;             // 98304 (dead after proj3#1 -> reused as PP)
  float* M26  = ws + 196608;            // 98304
  float* Z    = ws + 294912;            // 49152
  float* ZB   = ws + 344064;            // 49152
  int*   FLAG = (int*)(ws + 409600);    // 16
  int*   NBRP = (int*)(ws + 409616);    // 49152 ints
  int*   NBRG = (int*)(ws + 458768);    // 1,638,400 ints -> ends 2,097,168
  float* S0   = ws + 2097168;           // 4 slots x 2,097,152 floats (8 MB each)
  float* S1   = ws + 4194320;           // S0+S1 contiguous -> 16 MB G region
  float* S2   = ws + 6291472;
  float* S3   = ws + 8388624;           // ends 10,485,776 floats
  void*  WT   = (void*)S2;              // head W transpose (S2+S3 dead during head)
  float* PP   = M16;                    // pool partials (65536 floats, M16 dead then)

  detect_kernel<<<1, 64, 0, stream>>>((const unsigned short*)x, FLAG);
  convert_kernel<<<384, 256, 0, stream>>>(x, XF, Bg * Nn * Fdim, FLAG);
  knn100_kernel<<<Bg * Nn / 4, 256, 0, stream>>>(XF, NBRG);
  knn3_x_kernel<<<Bg * Nn / 16, 256, 0, stream>>>(XF, NBRP);

  // ---- TAG branch ----
  gm6_kernel<<<Bg, 512, 0, stream>>>(XF, NBRG, M16);
  gm6_kernel<<<Bg, 512, 0, stream>>>(M16, NBRG, M26);
  proj3_kernel<<<2048, 128, 0, stream>>>(XF, M16, M26, tag1_W, tag1_b, S0, 6, 0, 0, FLAG);
  pool1_kernel<<<256, 128, 0, stream>>>(S0, PP);
  pool2_kernel<<<Bg, 128, 0, stream>>>(PP, Z, 0, 128);

  gm128_kernel<<<Bg * Nn, 128, 0, stream>>>(S0, NBRG, S1);
  gm128_kernel<<<Bg * Nn, 128, 0, stream>>>(S1, NBRG, S2);
  proj3_kernel<<<2048, 128, 0, stream>>>(S0, S1, S2, tag_W, tag_b, S3, 128, 0, 0, FLAG);
  pool1_kernel<<<256, 128, 0, stream>>>(S3, PP);
  pool2_kernel<<<Bg, 128, 0, stream>>>(PP, Z, 256, 384);

  gm128_kernel<<<Bg * Nn, 128, 0, stream>>>(S3, NBRG, S1);
  gm128_kernel<<<Bg * Nn, 128, 0, stream>>>(S1, NBRG, S2);
  proj3_kernel<<<2048, 128, 0, stream>>>(S3, S1, S2, tag_W, tag_b, S0, 128,
                                         3L * 128 * 128, 128, FLAG);
  pool1_kernel<<<256, 128, 0, stream>>>(S0, PP);
  pool2_kernel<<<Bg, 128, 0, stream>>>(PP, Z, 512, 640);

  // ---- point branch ----
  proj_dual_kernel<<<2048, 128, 0, stream>>>(XF, p1_W1, S0, S1, 6, 0, FLAG);
  edge_mlp1_kernel<<<2048, 128, 0, stream>>>(S0, S1, NBRP, p1_W2, p1_b1, p1_b2, S2, FLAG);  // Y0=S2
  pool1_kernel<<<256, 128, 0, stream>>>(S2, PP);
  pool2_kernel<<<Bg, 128, 0, stream>>>(PP, Z, 768, 1152);

  for (int c = 0; c < Bg; c += GC16) {             // G=S0+S1 (U,V dead)
    gram_kernel<<<GC16 * 64, 256, 0, stream>>>(S2, S0, c);
    knn3_gram_kernel<<<GC16 * Nn / 16, 256, 0, stream>>>(S0, NBRP, c);
  }
  proj_dual_kernel<<<2048, 128, 0, stream>>>(S2, pf_W, S0, S1, 128, 0, FLAG);  // G dead
  edge_max_kernel<<<Bg * Nn, 128, 0, stream>>>(S0, S1, NBRP, pf_b, S3, 0, FLAG);  // Y1=S3
  pool1_kernel<<<256, 128, 0, stream>>>(S3, PP);
  pool2_kernel<<<Bg, 128, 0, stream>>>(PP, Z, 896, 1280);

  for (int c = 0; c < Bg; c += GC16) {             // G=S0+S1 (U,V dead)
    gram_kernel<<<GC16 * 64, 256, 0, stream>>>(S3, S0, c);
    knn3_gram_kernel<<<GC16 * Nn / 16, 256, 0, stream>>>(S0, NBRP, c);
  }
  proj_dual_kernel<<<2048, 128, 0, stream>>>(S3, pf_W, S0, S1, 128, 256L * 128, FLAG);  // G dead
  edge_max_kernel<<<Bg * Nn, 128, 0, stream>>>(S0, S1, NBRP, pf_b, S2, 128, FLAG);  // Y2=S2
  pool1_kernel<<<256, 128, 0, stream>>>(S2, PP);
  pool2_kernel<<<Bg, 128, 0, stream>>>(PP, Z, 1024, 1408);

  // ---- head ----
  bn_kernel<<<6, 256, 0, stream>>>(Z, bn_g, bn_b, FLAG);
  wtrans_kernel<<<2304, 256, 0, stream>>>(lin_W, WT, 0L * DIM2 * DIM2, FLAG);
  hl_kernel<<<192, 256, 0, stream>>>(Z, WT, lin_b, ZB, 0L * DIM2, FLAG);
  wtrans_kernel<<<2304, 256, 0, stream>>>(lin_W, WT, 1L * DIM2 * DIM2, FLAG);
  hl_kernel<<<192, 256, 0, stream>>>(ZB, WT, lin_b, Z, 1L * DIM2, FLAG);
  wtrans_kernel<<<2304, 256, 0, stream>>>(lin_W, WT, 2L * DIM2 * DIM2, FLAG);
  hl_kernel<<<192, 256, 0, stream>>>(Z, WT, lin_b, ZB, 2L * DIM2, FLAG);
  wtrans_kernel<<<2304, 256, 0, stream>>>(lin_W, WT, 3L * DIM2 * DIM2, FLAG);
  hl_kernel<<<192, 256, 0, stream>>>(ZB, WT, lin_b, Z, 3L * DIM2, FLAG);
  wtrans_kernel<<<2304, 256, 0, stream>>>(lin_W, WT, 4L * DIM2 * DIM2, FLAG);
  hl_kernel<<<192, 256, 0, stream>>>(Z, WT, lin_b, ZB, 4L * DIM2, FLAG);
  final_kernel<<<Bg, 256, 0, stream>>>(ZB, out_W, out_b, d_out, FLAG);
}

// Round 11
// 1037.170 us; speedup vs baseline: 1.0787x; 1.0787x over previous
//
#include <hip/hip_runtime.h>
#include <hip/hip_bf16.h>

#define Bg 32
#define Nn 512
#define Fdim 6
#define Wd 128
#define KG 100
#define KP 3
#define DIM2 1536
#define GC16 16

typedef __hip_bfloat16 bf16;
typedef unsigned long long ull;

__device__ __forceinline__ float b2f(bf16 v) { return __bfloat162float(v); }
__device__ __forceinline__ float h2f(unsigned short h) { return __uint_as_float((unsigned)h << 16); }
__device__ __forceinline__ float lrelu(float v) { return v > 0.0f ? v : 0.01f * v; }

// ---------- dtype detection (f32=1 / bf16=0) ----------
__global__ void detect_kernel(const unsigned short* __restrict__ x, int* __restrict__ flag) {
  if (threadIdx.x == 0 && blockIdx.x == 0) {
    int big = 0;
    for (int i = 0; i < 512; i += 2) {
      unsigned short u = x[i];
      int e = (u >> 7) & 0xFF;
      if (e >= 140) big++;
    }
    *flag = (big > 20) ? 1 : 0;
  }
}

// ---------- convert x -> f32 ----------
__global__ void convert_kernel(const void* __restrict__ x, float* __restrict__ xf, int n,
                               const int* __restrict__ flag) {
  int i = blockIdx.x * 256 + threadIdx.x;
  if (i >= n) return;
  if (*flag) xf[i] = ((const float*)x)[i];
  else       xf[i] = b2f(((const bf16*)x)[i]);
}

// ---------- branchless sorted-3 insert ----------
__device__ __forceinline__ void ins3b(ull key, ull& k0, ull& k1, ull& k2) {
  ull M0 = k0 < key ? key : k0;  k0 = k0 < key ? k0 : key;
  ull M1 = k1 < M0 ? M0 : k1;    k1 = k1 < M0 ? k1 : M0;
  k2 = k2 < M1 ? k2 : M1;
}

// ---------- kNN k=100: one wave/row; ballot-popcount radix search ----------
__global__ void knn100_kernel(const float* __restrict__ xf, int* __restrict__ nbr) {
  __shared__ float xg[Nn * 7];
  __shared__ float sqv[Nn];
  int t = threadIdx.x; int w = t >> 6; int l = t & 63;
  int row0 = blockIdx.x * 4; int g = row0 >> 9;
  const float* xp = xf + g * (Nn * Fdim);
  for (int j = t; j < Nn; j += 256) {
    float s = 0.0f;
    #pragma unroll
    for (int c = 0; c < Fdim; c++) { float v = xp[j * Fdim + c]; xg[j * 7 + c] = v; s += v * v; }
    sqv[j] = s;
  }
  __syncthreads();
  int i = (row0 & 511) + w;
  float xi[Fdim];
  #pragma unroll
  for (int c = 0; c < Fdim; c++) xi[c] = xg[i * 7 + c];
  float sqi = sqv[i];
  unsigned m[8];
  #pragma unroll
  for (int ch = 0; ch < 8; ch++) {
    int j = ch * 64 + l;
    float dot = 0.0f;
    #pragma unroll
    for (int c = 0; c < Fdim; c++) dot += xi[c] * xg[j * 7 + c];
    float d = sqi + sqv[j] - 2.0f * dot;
    if (j == i) d += 1e10f;
    unsigned u = __float_as_uint(d);
    m[ch] = (u & 0x80000000u) ? ~u : (u | 0x80000000u);
  }
  unsigned T = 0u;
  for (int b = 31; b >= 0; b--) {
    unsigned mid = T | (1u << b);
    int c = 0;
    #pragma unroll
    for (int ch = 0; ch < 8; ch++) c += __popcll(__ballot(m[ch] < mid));
    if (c < KG) T = mid;
  }
  int* outp = nbr + ((size_t)(g * Nn + i)) * KG;
  ull lmask = (1ull << l) - 1ull;
  int base = 0;
  #pragma unroll
  for (int ch = 0; ch < 8; ch++) {
    bool less = m[ch] < T;
    ull bal = __ballot(less);
    if (less) outp[base + __popcll(bal & lmask)] = ch * 64 + l;
    base += __popcll(bal);
  }
  int need = KG - base;
  int eqb = 0;
  #pragma unroll
  for (int ch = 0; ch < 8; ch++) {
    bool eq = (m[ch] == T);
    ull bal = __ballot(eq);
    int gr = eqb + __popcll(bal & lmask);
    if (eq && gr < need) outp[base + gr] = ch * 64 + l;
    eqb += __popcll(bal);
  }
}

// ---------- kNN k=3 on coords: 16 lanes/row ----------
__global__ void knn3_x_kernel(const float* __restrict__ xf, int* __restrict__ nbr) {
  __shared__ float xg[Nn * 7];
  __shared__ float sqv[Nn];
  int t = threadIdx.x; int bid = blockIdx.x;
  int g = bid >> 5;
  const float* xp = xf + g * (Nn * Fdim);
  for (int j = t; j < Nn; j += 256) {
    float s = 0.0f;
    #pragma unroll
    for (int c = 0; c < Fdim; c++) { float v = xp[j * Fdim + c]; xg[j * 7 + c] = v; s += v * v; }
    sqv[j] = s;
  }
  __syncthreads();
  int lr = t >> 4; int sub = t & 15; int l = t & 63;
  int i = ((bid & 31) << 4) + lr;
  float xi[Fdim];
  #pragma unroll
  for (int c = 0; c < Fdim; c++) xi[c] = xg[i * 7 + c];
  float sqi = sqv[i];
  ull k0 = ~0ull, k1 = ~0ull, k2 = ~0ull;
  for (int jj = 0; jj < 32; jj++) {
    int s = (jj + l) & 31;
    int j = sub * 32 + s;
    float dot = 0.0f;
    #pragma unroll
    for (int c = 0; c < Fdim; c++) dot += xi[c] * xg[j * 7 + c];
    float d = sqi + sqv[j] - 2.0f * dot;
    if (j == i) d += 1e10f;
    unsigned u = __float_as_uint(d);
    unsigned m = (u & 0x80000000u) ? ~u : (u | 0x80000000u);
    ins3b(((ull)m << 32) | (unsigned)j, k0, k1, k2);
  }
  #pragma unroll
  for (int off = 1; off <= 8; off <<= 1) {
    ull b0 = __shfl_xor(k0, off, 64);
    ull b1 = __shfl_xor(k1, off, 64);
    ull b2 = __shfl_xor(k2, off, 64);
    ins3b(b0, k0, k1, k2); ins3b(b1, k0, k1, k2); ins3b(b2, k0, k1, k2);
  }
  if (sub == 0) {
    int row = g * Nn + i;
    nbr[row * 3 + 0] = (int)(k0 & 0xFFFFFFFFu);
    nbr[row * 3 + 1] = (int)(k1 & 0xFFFFFFFFu);
    nbr[row * 3 + 2] = (int)(k2 & 0xFFFFFFFFu);
  }
}

// ---------- kNN k=3 from chunked Gram ----------
__global__ void knn3_gram_kernel(const float* __restrict__ G, int* __restrict__ nbr, int g0) {
  __shared__ float sqv[Nn];
  int t = threadIdx.x; int bid = blockIdx.x;
  int gl = bid >> 5; int g = g0 + gl;
  const float* Gg = G + (size_t)gl * Nn * Nn;
  for (int j = t; j < Nn; j += 256) sqv[j] = Gg[(size_t)j * Nn + j];
  __syncthreads();
  int lr = t >> 4; int sub = t & 15; int l = t & 63;
  int i = ((bid & 31) << 4) + lr;
  float sqi = sqv[i];
  const float* Gr = Gg + (size_t)i * Nn;
  ull k0 = ~0ull, k1 = ~0ull, k2 = ~0ull;
  for (int jj = 0; jj < 32; jj++) {
    int s = (jj + l) & 31;
    int j = sub * 32 + s;
    float d = sqi + sqv[j] - 2.0f * Gr[j];
    if (j == i) d += 1e10f;
    unsigned u = __float_as_uint(d);
    unsigned m = (u & 0x80000000u) ? ~u : (u | 0x80000000u);
    ins3b(((ull)m << 32) | (unsigned)j, k0, k1, k2);
  }
  #pragma unroll
  for (int off = 1; off <= 8; off <<= 1) {
    ull b0 = __shfl_xor(k0, off, 64);
    ull b1 = __shfl_xor(k1, off, 64);
    ull b2 = __shfl_xor(k2, off, 64);
    ins3b(b0, k0, k1, k2); ins3b(b1, k0, k1, k2); ins3b(b2, k0, k1, k2);
  }
  if (sub == 0) {
    int row = g * Nn + i;
    nbr[row * 3 + 0] = (int)(k0 & 0xFFFFFFFFu);
    nbr[row * 3 + 1] = (int)(k1 & 0xFFFFFFFFu);
    nbr[row * 3 + 2] = (int)(k2 & 0xFFFFFFFFu);
  }
}

// ---------- neighbor-mean over 100, C=6 ----------
__global__ void gm6_kernel(const float* __restrict__ src, const int* __restrict__ nbr,
                           float* __restrict__ dst) {
  __shared__ float s[Nn * Fdim];
  int g = blockIdx.x; int t = threadIdx.x;  // 512
  const float* sp = src + g * (Nn * Fdim);
  for (int idx = t; idx < Nn * Fdim; idx += 512) s[idx] = sp[idx];
  __syncthreads();
  float acc[Fdim] = {0, 0, 0, 0, 0, 0};
  const int* nb = nbr + ((size_t)(g * Nn + t)) * KG;
  for (int k = 0; k < KG; k++) {
    int j = nb[k];
    #pragma unroll
    for (int c = 0; c < Fdim; c++) acc[c] += s[j * Fdim + c];
  }
  float* dp = dst + (size_t)(g * Nn + t) * Fdim;
  #pragma unroll
  for (int c = 0; c < Fdim; c++) dp[c] = acc[c] / 100.0f;
}

// ---------- neighbor-mean over 100, C=128 ----------
__global__ void gm128_kernel(const float* __restrict__ src, const int* __restrict__ nbr,
                             float* __restrict__ dst) {
  __shared__ int ids[KG];
  int row = blockIdx.x; int g = row >> 9; int t = threadIdx.x;  // 128
  if (t < KG) ids[t] = nbr[(size_t)row * KG + t];
  __syncthreads();
  const float* sp = src + (size_t)g * Nn * Wd;
  float acc = 0.0f;
  #pragma unroll 4
  for (int k = 0; k < KG; k++) acc += sp[ids[k] * Wd + t];
  dst[(size_t)row * Wd + t] = acc / 100.0f;
}

// ---------- proj3 small (C=6 only; proven r10 path) ----------
__global__ void proj3_kernel(const float* __restrict__ in0, const float* __restrict__ in1,
                             const float* __restrict__ in2, const void* __restrict__ Wt_,
                             const void* __restrict__ bt_, float* __restrict__ out,
                             const int* __restrict__ flag) {
  __shared__ float s0[48], s1[48], s2[48];
  int t = threadIdx.x;  // 128
  int node0 = blockIdx.x * 8;
  int f32 = *flag;
  float acc[8] = {0, 0, 0, 0, 0, 0, 0, 0};
  float bd;
  if (t < 48) {
    s0[t] = in0[(size_t)node0 * 6 + t];
    s1[t] = in1[(size_t)node0 * 6 + t];
    s2[t] = in2[(size_t)node0 * 6 + t];
  }
  __syncthreads();
  if (f32) {
    const float* W = (const float*)Wt_;
    for (int c = 0; c < 6; c++) {
      float w0 = W[c * 128 + t], w1 = W[(6 + c) * 128 + t], w2 = W[(12 + c) * 128 + t];
      #pragma unroll
      for (int n = 0; n < 8; n++)
        acc[n] += s0[n * 6 + c] * w0 + s1[n * 6 + c] * w1 + s2[n * 6 + c] * w2;
    }
    bd = ((const float*)bt_)[t];
  } else {
    const bf16* W = (const bf16*)Wt_;
    for (int c = 0; c < 6; c++) {
      float w0 = b2f(W[c * 128 + t]), w1 = b2f(W[(6 + c) * 128 + t]), w2 = b2f(W[(12 + c) * 128 + t]);
      #pragma unroll
      for (int n = 0; n < 8; n++)
        acc[n] += s0[n * 6 + c] * w0 + s1[n * 6 + c] * w1 + s2[n * 6 + c] * w2;
    }
    bd = b2f(((const bf16*)bt_)[t]);
  }
  #pragma unroll
  for (int n = 0; n < 8; n++)
    out[(size_t)(node0 + n) * 128 + t] = lrelu(acc[n] + bd);
}

// ---------- proj3 big (C=128): register-tiled, 32 nodes x 128 cols per block ----------
// thread = 4 nodes x 4 cols; LDS amplification 32x (was 128x)
__global__ void proj3_big_kernel(const float* __restrict__ in0, const float* __restrict__ in1,
                                 const float* __restrict__ in2, const void* __restrict__ Wt_,
                                 const void* __restrict__ bt_, float* __restrict__ out,
                                 long Woff, long boff, const int* __restrict__ flag) {
  __shared__ __align__(16) float sa[3][32 * 128];  // 48 KB
  int t = threadIdx.x;  // 256
  int node0 = blockIdx.x * 32;
  int f32 = *flag;
  {
    const float4* q0 = (const float4*)(in0 + (size_t)node0 * 128);
    const float4* q1 = (const float4*)(in1 + (size_t)node0 * 128);
    const float4* q2 = (const float4*)(in2 + (size_t)node0 * 128);
    float4* s0 = (float4*)sa[0]; float4* s1 = (float4*)sa[1]; float4* s2 = (float4*)sa[2];
    #pragma unroll
    for (int it = 0; it < 4; it++) {
      s0[t + it * 256] = q0[t + it * 256];
      s1[t + it * 256] = q1[t + it * 256];
      s2[t + it * 256] = q2[t + it * 256];
    }
  }
  __syncthreads();
  int tx = t & 31, ty = t >> 5;
  int col0 = tx * 4, n0 = ty * 4;
  float acc[4][4];
  #pragma unroll
  for (int n = 0; n < 4; n++)
    #pragma unroll
    for (int j = 0; j < 4; j++) acc[n][j] = 0.0f;
  if (f32) {
    const float* W = (const float*)Wt_ + Woff;
    for (int a = 0; a < 3; a++) {
      const float* sp = sa[a];
      const float* Wa = W + (size_t)a * 128 * 128;
      for (int c0 = 0; c0 < 128; c0 += 4) {
        float wv[4][4];
        #pragma unroll
        for (int cc = 0; cc < 4; cc++) {
          float4 w4 = *(const float4*)&Wa[(c0 + cc) * 128 + col0];
          wv[cc][0] = w4.x; wv[cc][1] = w4.y; wv[cc][2] = w4.z; wv[cc][3] = w4.w;
        }
        #pragma unroll
        for (int n = 0; n < 4; n++) {
          float4 av = *(const float4*)&sp[(n0 + n) * 128 + c0];
          #pragma unroll
          for (int j = 0; j < 4; j++)
            acc[n][j] += av.x * wv[0][j] + av.y * wv[1][j] + av.z * wv[2][j] + av.w * wv[3][j];
        }
      }
    }
  } else {
    const unsigned short* W = (const unsigned short*)Wt_ + Woff;
    for (int a = 0; a < 3; a++) {
      const float* sp = sa[a];
      const unsigned short* Wa = W + (size_t)a * 128 * 128;
      for (int c0 = 0; c0 < 128; c0 += 4) {
        float wv[4][4];
        #pragma unroll
        for (int cc = 0; cc < 4; cc++) {
          ushort4 w4 = *(const ushort4*)&Wa[(c0 + cc) * 128 + col0];
          wv[cc][0] = h2f(w4.x); wv[cc][1] = h2f(w4.y); wv[cc][2] = h2f(w4.z); wv[cc][3] = h2f(w4.w);
        }
        #pragma unroll
        for (int n = 0; n < 4; n++) {
          float4 av = *(const float4*)&sp[(n0 + n) * 128 + c0];
          #pragma unroll
          for (int j = 0; j < 4; j++)
            acc[n][j] += av.x * wv[0][j] + av.y * wv[1][j] + av.z * wv[2][j] + av.w * wv[3][j];
        }
      }
    }
  }
  float bdv[4];
  if (f32) {
    const float* bt = (const float*)bt_ + boff;
    #pragma unroll
    for (int j = 0; j < 4; j++) bdv[j] = bt[col0 + j];
  } else {
    const bf16* bt = (const bf16*)bt_ + boff;
    #pragma unroll
    for (int j = 0; j < 4; j++) bdv[j] = b2f(bt[col0 + j]);
  }
  #pragma unroll
  for (int n = 0; n < 4; n++) {
    float4 ov;
    ov.x = lrelu(acc[n][0] + bdv[0]); ov.y = lrelu(acc[n][1] + bdv[1]);
    ov.z = lrelu(acc[n][2] + bdv[2]); ov.w = lrelu(acc[n][3] + bdv[3]);
    *(float4*)&out[(size_t)(node0 + n0 + n) * 128 + col0] = ov;
  }
}

// ---------- proj_dual small (C=6 only; proven r10 path) ----------
__global__ void proj_dual_kernel(const float* __restrict__ in, const void* __restrict__ Wt_,
                                 float* __restrict__ u, float* __restrict__ v,
                                 const int* __restrict__ flag) {
  __shared__ float s0[48];
  int t = threadIdx.x; int node0 = blockIdx.x * 8;
  int f32 = *flag;
  float au[8] = {0, 0, 0, 0, 0, 0, 0, 0};
  float av[8] = {0, 0, 0, 0, 0, 0, 0, 0};
  if (t < 48) s0[t] = in[(size_t)node0 * 6 + t];
  __syncthreads();
  if (f32) {
    const float* W = (const float*)Wt_;
    for (int c = 0; c < 6; c++) {
      float wa = W[c * 128 + t], wb = W[(6 + c) * 128 + t];
      #pragma unroll
      for (int n = 0; n < 8; n++) { float x = s0[n * 6 + c]; au[n] += x * wa; av[n] += x * wb; }
    }
  } else {
    const bf16* W = (const bf16*)Wt_;
    for (int c = 0; c < 6; c++) {
      float wa = b2f(W[c * 128 + t]), wb = b2f(W[(6 + c) * 128 + t]);
      #pragma unroll
      for (int n = 0; n < 8; n++) { float x = s0[n * 6 + c]; au[n] += x * wa; av[n] += x * wb; }
    }
  }
  #pragma unroll
  for (int n = 0; n < 8; n++) {
    u[(size_t)(node0 + n) * 128 + t] = au[n];
    v[(size_t)(node0 + n) * 128 + t] = av[n];
  }
}

// ---------- proj_dual big (C=128): register-tiled ----------
__global__ void proj_dual_big_kernel(const float* __restrict__ in, const void* __restrict__ Wt_,
                                     float* __restrict__ u, float* __restrict__ v,
                                     long Woff, const int* __restrict__ flag) {
  __shared__ __align__(16) float sa[32 * 128];  // 16 KB
  int t = threadIdx.x;  // 256
  int node0 = blockIdx.x * 32;
  int f32 = *flag;
  {
    const float4* qp = (const float4*)(in + (size_t)node0 * 128);
    float4* s0 = (float4*)sa;
    #pragma unroll
    for (int it = 0; it < 4; it++) s0[t + it * 256] = qp[t + it * 256];
  }
  __syncthreads();
  int tx = t & 31, ty = t >> 5;
  int col0 = tx * 4, n0 = ty * 4;
  float accu[4][4], accv[4][4];
  #pragma unroll
  for (int n = 0; n < 4; n++)
    #pragma unroll
    for (int j = 0; j < 4; j++) { accu[n][j] = 0.0f; accv[n][j] = 0.0f; }
  if (f32) {
    const float* W = (const float*)Wt_ + Woff;
    for (int c0 = 0; c0 < 128; c0 += 4) {
      float wa[4][4], wb[4][4];
      #pragma unroll
      for (int cc = 0; cc < 4; cc++) {
        float4 a4 = *(const float4*)&W[(c0 + cc) * 128 + col0];
        float4 b4 = *(const float4*)&W[(128 + c0 + cc) * 128 + col0];
        wa[cc][0] = a4.x; wa[cc][1] = a4.y; wa[cc][2] = a4.z; wa[cc][3] = a4.w;
        wb[cc][0] = b4.x; wb[cc][1] = b4.y; wb[cc][2] = b4.z; wb[cc][3] = b4.w;
      }
      #pragma unroll
      for (int n = 0; n < 4; n++) {
        float4 av = *(const float4*)&sa[(n0 + n) * 128 + c0];
        #pragma unroll
        for (int j = 0; j < 4; j++) {
          accu[n][j] += av.x * wa[0][j] + av.y * wa[1][j] + av.z * wa[2][j] + av.w * wa[3][j];
          accv[n][j] += av.x * wb[0][j] + av.y * wb[1][j] + av.z * wb[2][j] + av.w * wb[3][j];
        }
      }
    }
  } else {
    const unsigned short* W = (const unsigned short*)Wt_ + Woff;
    for (int c0 = 0; c0 < 128; c0 += 4) {
      float wa[4][4], wb[4][4];
      #pragma unroll
      for (int cc = 0; cc < 4; cc++) {
        ushort4 a4 = *(const ushort4*)&W[(c0 + cc) * 128 + col0];
        ushort4 b4 = *(const ushort4*)&W[(128 + c0 + cc) * 128 + col0];
        wa[cc][0] = h2f(a4.x); wa[cc][1] = h2f(a4.y); wa[cc][2] = h2f(a4.z); wa[cc][3] = h2f(a4.w);
        wb[cc][0] = h2f(b4.x); wb[cc][1] = h2f(b4.y); wb[cc][2] = h2f(b4.z); wb[cc][3] = h2f(b4.w);
      }
      #pragma unroll
      for (int n = 0; n < 4; n++) {
        float4 av = *(const float4*)&sa[(n0 + n) * 128 + c0];
        #pragma unroll
        for (int j = 0; j < 4; j++) {
          accu[n][j] += av.x * wa[0][j] + av.y * wa[1][j] + av.z * wa[2][j] + av.w * wa[3][j];
          accv[n][j] += av.x * wb[0][j] + av.y * wb[1][j] + av.z * wb[2][j] + av.w * wb[3][j];
        }
      }
    }
  }
  #pragma unroll
  for (int n = 0; n < 4; n++) {
    *(float4*)&u[(size_t)(node0 + n0 + n) * 128 + col0] = *(float4*)accu[n];
    *(float4*)&v[(size_t)(node0 + n0 + n) * 128 + col0] = *(float4*)accv[n];
  }
}

// ---------- edgeconv1: float4 tl reads + batched weight loads ----------
__global__ void edge_mlp1_kernel(const float* __restrict__ u, const float* __restrict__ v,
                                 const int* __restrict__ nbrp, const void* __restrict__ W2_,
                                 const void* __restrict__ b1_, const void* __restrict__ b2_,
                                 float* __restrict__ y, const int* __restrict__ flag) {
  __shared__ __align__(16) float tl[8][3][128];
  int t = threadIdx.x; int node0 = blockIdx.x * 8; int g = node0 >> 9;
  int f32 = *flag;
  float b1d;
  if (f32) b1d = ((const float*)b1_)[t]; else b1d = b2f(((const bf16*)b1_)[t]);
  for (int n = 0; n < 8; n++) {
    int row = node0 + n;
    float ui = u[(size_t)row * 128 + t], vi = v[(size_t)row * 128 + t];
    #pragma unroll
    for (int k = 0; k < 3; k++) {
      int j = nbrp[row * 3 + k];
      tl[n][k][t] = lrelu(ui + v[(size_t)(g * Nn + j) * 128 + t] - vi + b1d);
    }
  }
  __syncthreads();
  float acc[8][3];
  #pragma unroll
  for (int n = 0; n < 8; n++)
    #pragma unroll
    for (int k = 0; k < 3; k++) acc[n][k] = 0.0f;
  if (f32) {
    const float* W = (const float*)W2_;
    for (int c0 = 0; c0 < 128; c0 += 4) {
      float wv[4];
      #pragma unroll
      for (int q = 0; q < 4; q++) wv[q] = W[(c0 + q) * 128 + t];
      #pragma unroll
      for (int n = 0; n < 8; n++)
        #pragma unroll
        for (int k = 0; k < 3; k++) {
          float4 tv = *(const float4*)&tl[n][k][c0];
          acc[n][k] += tv.x * wv[0] + tv.y * wv[1] + tv.z * wv[2] + tv.w * wv[3];
        }
    }
  } else {
    const bf16* W = (const bf16*)W2_;
    for (int c0 = 0; c0 < 128; c0 += 4) {
      float wv[4];
      #pragma unroll
      for (int q = 0; q < 4; q++) wv[q] = b2f(W[(c0 + q) * 128 + t]);
      #pragma unroll
      for (int n = 0; n < 8; n++)
        #pragma unroll
        for (int k = 0; k < 3; k++) {
          float4 tv = *(const float4*)&tl[n][k][c0];
          acc[n][k] += tv.x * wv[0] + tv.y * wv[1] + tv.z * wv[2] + tv.w * wv[3];
        }
    }
  }
  float b2d;
  if (f32) b2d = ((const float*)b2_)[t]; else b2d = b2f(((const bf16*)b2_)[t]);
  #pragma unroll
  for (int n = 0; n < 8; n++) {
    float m = lrelu(acc[n][0] + b2d);
    m = fmaxf(m, lrelu(acc[n][1] + b2d));
    m = fmaxf(m, lrelu(acc[n][2] + b2d));
    y[(size_t)(node0 + n) * 128 + t] = m;
  }
}

// ---------- edgeconv2/3 ----------
__global__ void edge_max_kernel(const float* __restrict__ u, const float* __restrict__ v,
                                const int* __restrict__ nbrp, const void* __restrict__ bias_,
                                float* __restrict__ y, long boff, const int* __restrict__ flag) {
  int row = blockIdx.x; int g = row >> 9; int t = threadIdx.x;  // 128
  float ui = u[(size_t)row * 128 + t], vi = v[(size_t)row * 128 + t];
  float bd;
  if (*flag) bd = ((const float*)bias_ + boff)[t]; else bd = b2f(((const bf16*)bias_ + boff)[t]);
  float m = -3.4e38f;
  #pragma unroll
  for (int k = 0; k < 3; k++) {
    int j = nbrp[row * 3 + k];
    m = fmaxf(m, lrelu(ui - vi + v[(size_t)(g * Nn + j) * 128 + t] + bd));
  }
  y[(size_t)row * 128 + t] = m;
}

// ---------- chunked Gram matrix ----------
__global__ void gram_kernel(const float* __restrict__ y, float* __restrict__ G, int g0) {
  __shared__ float As[64][17], Bs[64][17];
  int bid = blockIdx.x;
  int gl = bid >> 6; int tt = bid & 63; int ti = tt >> 3; int tj = tt & 7;
  int g = g0 + gl;
  int t = threadIdx.x; int tx = t & 15, ty = t >> 4;
  const float* Yg = y + (size_t)g * Nn * Wd;
  float* Gg = G + (size_t)gl * Nn * Nn;
  float c[4][4];
  #pragma unroll
  for (int p = 0; p < 4; p++)
    #pragma unroll
    for (int q = 0; q < 4; q++) c[p][q] = 0.0f;
  for (int k0 = 0; k0 < 128; k0 += 16) {
    for (int idx = t; idx < 1024; idx += 256) {
      int r = idx >> 4, cc = idx & 15;
      As[r][cc] = Yg[(ti * 64 + r) * 128 + k0 + cc];
      Bs[r][cc] = Yg[(tj * 64 + r) * 128 + k0 + cc];
    }
    __syncthreads();
    for (int kk = 0; kk < 16; kk++) {
      float a[4], bb[4];
      #pragma unroll
      for (int p = 0; p < 4; p++) a[p] = As[ty * 4 + p][kk];
      #pragma unroll
      for (int q = 0; q < 4; q++) bb[q] = Bs[tx * 4 + q][kk];
      #pragma unroll
      for (int p = 0; p < 4; p++)
        #pragma unroll
        for (int q = 0; q < 4; q++) c[p][q] += a[p] * bb[q];
    }
    __syncthreads();
  }
  #pragma unroll
  for (int p = 0; p < 4; p++)
    #pragma unroll
    for (int q = 0; q < 4; q++)
      Gg[(size_t)(ti * 64 + ty * 4 + p) * Nn + tj * 64 + tx * 4 + q] = c[p][q];
}

// ---------- two-pass mean+max pool ----------
__global__ void pool1_kernel(const float* __restrict__ h, float* __restrict__ pp) {
  int b = blockIdx.x;                 // 256: g*8 + chunk
  int g = b >> 3, ch = b & 7;
  int t = threadIdx.x;                // 128
  const float* hg = h + (size_t)g * Nn * Wd + (size_t)ch * 64 * Wd;
  float s = 0.0f, m = -3.4e38f;
  #pragma unroll 4
  for (int n = 0; n < 64; n++) {
    float vv = hg[n * 128 + t];
    s += vv; m = fmaxf(m, vv);
  }
  pp[b * 256 + t] = s;
  pp[b * 256 + 128 + t] = m;
}

__global__ void pool2_kernel(const float* __restrict__ pp, float* __restrict__ z,
                             int meanoff, int maxoff) {
  int g = blockIdx.x; int t = threadIdx.x;  // 128
  float s = 0.0f, m = -3.4e38f;
  #pragma unroll
  for (int q = 0; q < 8; q++) {
    s += pp[(g * 8 + q) * 256 + t];
    m = fmaxf(m, pp[(g * 8 + q) * 256 + 128 + t]);
  }
  z[g * DIM2 + meanoff + t] = s / 512.0f;
  z[g * DIM2 + maxoff + t] = m;
}

// ---------- BatchNorm1d (batch stats), in place ----------
__global__ void bn_kernel(float* __restrict__ z, const void* __restrict__ gamma,
                          const void* __restrict__ beta, const int* __restrict__ flag) {
  int c = blockIdx.x * 256 + threadIdx.x;
  if (c >= DIM2) return;
  float s = 0.0f;
  for (int r = 0; r < Bg; r++) s += z[r * DIM2 + c];
  float mu = s / 32.0f;
  float v = 0.0f;
  for (int r = 0; r < Bg; r++) { float d = z[r * DIM2 + c] - mu; v += d * d; }
  float var = v / 32.0f;
  float gm, bt;
  if (*flag) { gm = ((const float*)gamma)[c]; bt = ((const float*)beta)[c]; }
  else       { gm = b2f(((const bf16*)gamma)[c]); bt = b2f(((const bf16*)beta)[c]); }
  float scale = gm / sqrtf(var + 1e-5f);
  for (int r = 0; r < Bg; r++) z[r * DIM2 + c] = (z[r * DIM2 + c] - mu) * scale + bt;
}

// ---------- W transpose: WT[d][k] = W[k][d], 32x32 LDS tiles ----------
__global__ void wtrans_kernel(const void* __restrict__ W_, void* __restrict__ WT_,
                              long Woff, const int* __restrict__ flag) {
  __shared__ float tf[32][33];
  __shared__ unsigned short th[32][33];
  int bx = blockIdx.x % 48, by = blockIdx.x / 48;
  int tx = threadIdx.x & 31, ty = threadIdx.x >> 5; // 32 x 8
  if (*flag) {
    const float* W = (const float*)W_ + Woff;
    float* WT = (float*)WT_;
    #pragma unroll
    for (int r = 0; r < 32; r += 8)
      tf[ty + r][tx] = W[(size_t)(by * 32 + ty + r) * DIM2 + bx * 32 + tx];
    __syncthreads();
    #pragma unroll
    for (int r = 0; r < 32; r += 8)
      WT[(size_t)(bx * 32 + ty + r) * DIM2 + by * 32 + tx] = tf[tx][ty + r];
  } else {
    const unsigned short* W = (const unsigned short*)W_ + Woff;
    unsigned short* WT = (unsigned short*)WT_;
    #pragma unroll
    for (int r = 0; r < 32; r += 8)
      th[ty + r][tx] = W[(size_t)(by * 32 + ty + r) * DIM2 + bx * 32 + tx];
    __syncthreads();
    #pragma unroll
    for (int r = 0; r < 32; r += 8)
      WT[(size_t)(bx * 32 + ty + r) * DIM2 + by * 32 + tx] = th[tx][ty + r];
  }
}

// ---------- head linear: float4 LDS reads + batched WT loads ----------
__global__ void hl_kernel(const float* __restrict__ in, const void* __restrict__ WTt,
                          const void* __restrict__ bt_, float* __restrict__ out,
                          long boff, const int* __restrict__ flag) {
  __shared__ __align__(16) float a[32 * 132];
  int t = threadIdx.x; int dcol = blockIdx.x * 8 + (t >> 5); int r = t & 31;
  int f32 = *flag;
  float acc = 0.0f;
  for (int k0 = 0; k0 < DIM2; k0 += 128) {
    for (int idx = t; idx < 4096; idx += 256) {
      int rr = idx >> 7, kk = idx & 127;
      a[rr * 132 + kk] = in[rr * DIM2 + k0 + kk];
    }
    __syncthreads();
    if (f32) {
      const float* WT = (const float*)WTt;
      for (int kk = 0; kk < 128; kk += 4) {
        float wv[4];
        #pragma unroll
        for (int q = 0; q < 4; q++) wv[q] = WT[(size_t)dcol * DIM2 + k0 + kk + q];
        float4 av = *(const float4*)&a[r * 132 + kk];
        acc += av.x * wv[0] + av.y * wv[1] + av.z * wv[2] + av.w * wv[3];
      }
    } else {
      const bf16* WT = (const bf16*)WTt;
      for (int kk = 0; kk < 128; kk += 4) {
        float wv[4];
        #pragma unroll
        for (int q = 0; q < 4; q++) wv[q] = b2f(WT[(size_t)dcol * DIM2 + k0 + kk + q]);
        float4 av = *(const float4*)&a[r * 132 + kk];
        acc += av.x * wv[0] + av.y * wv[1] + av.z * wv[2] + av.w * wv[3];
      }
    }
    __syncthreads();
  }
  float bd;
  if (f32) bd = ((const float*)bt_ + boff)[dcol]; else bd = b2f(((const bf16*)bt_ + boff)[dcol]);
  out[r * DIM2 + dcol] = lrelu(acc + bd);
}

// ---------- final ----------
__global__ void final_kernel(const float* __restrict__ zin, const void* __restrict__ outW,
                             const void* __restrict__ outb, void* __restrict__ out,
                             const int* __restrict__ flag) {
  __shared__ float red[256];
  int r = blockIdx.x, t = threadIdx.x;
  int f32 = *flag;
  float acc = 0.0f;
  if (f32) {
    const float* W = (const float*)outW;
    for (int c = t; c < DIM2; c += 256) acc += zin[r * DIM2 + c] * W[c];
  } else {
    const bf16* W = (const bf16*)outW;
    for (int c = t; c < DIM2; c += 256) acc += zin[r * DIM2 + c] * b2f(W[c]);
  }
  red[t] = acc; __syncthreads();
  for (int s = 128; s > 0; s >>= 1) { if (t < s) red[t] += red[t + s]; __syncthreads(); }
  if (t == 0) {
    float ob;
    if (f32) ob = ((const float*)outb)[0]; else ob = b2f(((const bf16*)outb)[0]);
    float val = red[0] + ob;
    if (f32) ((float*)out)[r] = val;
    else     ((bf16*)out)[r] = __float2bfloat16(val);
  }
}

extern "C" void kernel_launch(void* const* d_in, const int* in_sizes, int n_in,
                              void* d_out, int out_size, void* d_ws, size_t ws_size,
                              hipStream_t stream) {
  const void* x      = d_in[0];
  const void* tag1_W = d_in[2];
  const void* tag1_b = d_in[3];
  const void* tag_W  = d_in[4];
  const void* tag_b  = d_in[5];
  const void* p1_W1  = d_in[6];
  const void* p1_b1  = d_in[7];
  const void* p1_W2  = d_in[8];
  const void* p1_b2  = d_in[9];
  const void* pf_W   = d_in[10];
  const void* pf_b   = d_in[11];
  const void* bn_g   = d_in[12];
  const void* bn_b   = d_in[13];
  const void* lin_W  = d_in[14];
  const void* lin_b  = d_in[15];
  const void* out_W  = d_in[16];
  const void* out_b  = d_in[17];

  // ---- workspace layout: total 10,485,776 floats ≈ 40 MB ----
  float* ws = (float*)d_ws;
  float* XF   = ws + 0;                 // 98304
  float* M16  = ws + 98304;             // 98304 (dead after proj3 C=6 -> reused as PP)
  float* M26  = ws + 196608;            // 98304
  float* Z    = ws + 294912;            // 49152
  float* ZB   = ws + 344064;            // 49152
  int*   FLAG = (int*)(ws + 409600);    // 16
  int*   NBRP = (int*)(ws + 409616);    // 49152 ints
  int*   NBRG = (int*)(ws + 458768);    // 1,638,400 ints -> ends 2,097,168
  float* S0   = ws + 2097168;           // 4 slots x 2,097,152 floats (8 MB each)
  float* S1   = ws + 4194320;           // S0+S1 contiguous -> 16 MB G region
  float* S2   = ws + 6291472;
  float* S3   = ws + 8388624;           // ends 10,485,776 floats
  void*  WT   = (void*)S2;              // head W transpose (S2+S3 dead during head)
  float* PP   = M16;                    // pool partials (65536 floats)

  detect_kernel<<<1, 64, 0, stream>>>((const unsigned short*)x, FLAG);
  convert_kernel<<<384, 256, 0, stream>>>(x, XF, Bg * Nn * Fdim, FLAG);
  knn100_kernel<<<Bg * Nn / 4, 256, 0, stream>>>(XF, NBRG);
  knn3_x_kernel<<<Bg * Nn / 16, 256, 0, stream>>>(XF, NBRP);

  // ---- TAG branch ----
  gm6_kernel<<<Bg, 512, 0, stream>>>(XF, NBRG, M16);
  gm6_kernel<<<Bg, 512, 0, stream>>>(M16, NBRG, M26);
  proj3_kernel<<<2048, 128, 0, stream>>>(XF, M16, M26, tag1_W, tag1_b, S0, FLAG);
  pool1_kernel<<<256, 128, 0, stream>>>(S0, PP);
  pool2_kernel<<<Bg, 128, 0, stream>>>(PP, Z, 0, 128);

  gm128_kernel<<<Bg * Nn, 128, 0, stream>>>(S0, NBRG, S1);
  gm128_kernel<<<Bg * Nn, 128, 0, stream>>>(S1, NBRG, S2);
  proj3_big_kernel<<<512, 256, 0, stream>>>(S0, S1, S2, tag_W, tag_b, S3, 0, 0, FLAG);
  pool1_kernel<<<256, 128, 0, stream>>>(S3, PP);
  pool2_kernel<<<Bg, 128, 0, stream>>>(PP, Z, 256, 384);

  gm128_kernel<<<Bg * Nn, 128, 0, stream>>>(S3, NBRG, S1);
  gm128_kernel<<<Bg * Nn, 128, 0, stream>>>(S1, NBRG, S2);
  proj3_big_kernel<<<512, 256, 0, stream>>>(S3, S1, S2, tag_W, tag_b, S0,
                                            3L * 128 * 128, 128, FLAG);
  pool1_kernel<<<256, 128, 0, stream>>>(S0, PP);
  pool2_kernel<<<Bg, 128, 0, stream>>>(PP, Z, 512, 640);

  // ---- point branch ----
  proj_dual_kernel<<<2048, 128, 0, stream>>>(XF, p1_W1, S0, S1, FLAG);
  edge_mlp1_kernel<<<2048, 128, 0, stream>>>(S0, S1, NBRP, p1_W2, p1_b1, p1_b2, S2, FLAG);  // Y0=S2
  pool1_kernel<<<256, 128, 0, stream>>>(S2, PP);
  pool2_kernel<<<Bg, 128, 0, stream>>>(PP, Z, 768, 1152);

  for (int c = 0; c < Bg; c += GC16) {             // G=S0+S1 (U,V dead)
    gram_kernel<<<GC16 * 64, 256, 0, stream>>>(S2, S0, c);
    knn3_gram_kernel<<<GC16 * Nn / 16, 256, 0, stream>>>(S0, NBRP, c);
  }
  proj_dual_big_kernel<<<512, 256, 0, stream>>>(S2, pf_W, S0, S1, 0, FLAG);  // G dead
  edge_max_kernel<<<Bg * Nn, 128, 0, stream>>>(S0, S1, NBRP, pf_b, S3, 0, FLAG);  // Y1=S3
  pool1_kernel<<<256, 128, 0, stream>>>(S3, PP);
  pool2_kernel<<<Bg, 128, 0, stream>>>(PP, Z, 896, 1280);

  for (int c = 0; c < Bg; c += GC16) {             // G=S0+S1 (U,V dead)
    gram_kernel<<<GC16 * 64, 256, 0, stream>>>(S3, S0, c);
    knn3_gram_kernel<<<GC16 * Nn / 16, 256, 0, stream>>>(S0, NBRP, c);
  }
  proj_dual_big_kernel<<<512, 256, 0, stream>>>(S3, pf_W, S0, S1, 256L * 128, FLAG);  // G dead
  edge_max_kernel<<<Bg * Nn, 128, 0, stream>>>(S0, S1, NBRP, pf_b, S2, 128, FLAG);  // Y2=S2
  pool1_kernel<<<256, 128, 0, stream>>>(S2, PP);
  pool2_kernel<<<Bg, 128, 0, stream>>>(PP, Z, 1024, 1408);

  // ---- head ----
  bn_kernel<<<6, 256, 0, stream>>>(Z, bn_g, bn_b, FLAG);
  wtrans_kernel<<<2304, 256, 0, stream>>>(lin_W, WT, 0L * DIM2 * DIM2, FLAG);
  hl_kernel<<<192, 256, 0, stream>>>(Z, WT, lin_b, ZB, 0L * DIM2, FLAG);
  wtrans_kernel<<<2304, 256, 0, stream>>>(lin_W, WT, 1L * DIM2 * DIM2, FLAG);
  hl_kernel<<<192, 256, 0, stream>>>(ZB, WT, lin_b, Z, 1L * DIM2, FLAG);
  wtrans_kernel<<<2304, 256, 0, stream>>>(lin_W, WT, 2L * DIM2 * DIM2, FLAG);
  hl_kernel<<<192, 256, 0, stream>>>(Z, WT, lin_b, ZB, 2L * DIM2, FLAG);
  wtrans_kernel<<<2304, 256, 0, stream>>>(lin_W, WT, 3L * DIM2 * DIM2, FLAG);
  hl_kernel<<<192, 256, 0, stream>>>(ZB, WT, lin_b, Z, 3L * DIM2, FLAG);
  wtrans_kernel<<<2304, 256, 0, stream>>>(lin_W, WT, 4L * DIM2 * DIM2, FLAG);
  hl_kernel<<<192, 256, 0, stream>>>(Z, WT, lin_b, ZB, 4L * DIM2, FLAG);
  final_kernel<<<Bg, 256, 0, stream>>>(ZB, out_W, out_b, d_out, FLAG);
}